// Round 9
// baseline (211.491 us; speedup 1.0000x reference)
//
#include <hip/hip_runtime.h>
#include <math.h>

// loss = mean_b[ 0.5*nrmse(o1,t1) + 0.25*nrmse(o2,t2) + 0.25*nrmse(o3,t3) ]
// B=4096 rows, N=2048 fp32. 201.3 MB in, 4 B out.
//
// R1/R5/R7: three independent structures pin at ~2.8 TB/s read (10.9 GB/s/CU).
//   Effective in-service bytes = 10.9 GB/s x ~375ns ~ 4 KB/CU ~ 32 lines ->
//   per-CU outstanding-miss window; BW = window / avg_latency.
// R6/R8: persistent pipeline attempts VOIDED by spill — allocator caps at
//   VGPR=80 unless launch_bounds(BLOCK,1) explicitly lifts the occupancy
//   heuristic (R8 proved NO-arg still caps at 80; 20.7 MB scratch traffic).
// R9: spill-free persistent pipeline + latency-side levers:
//   - half-row sets: 8 loads/set, 2 sets = 64 data VGPRs (fits, no spill)
//   - __launch_bounds__(256,1): uncap VGPR budget
//   - counted vmcnt(8): 16 loads continuously outstanding, drain only at end
//   - 2048 waves x 6 CONTIGUOUS rows each: 3x fewer concurrent DRAM streams
//   - XCD-contiguous block swizzle: each XCD reads one contiguous ~25 MB span
constexpr int N_ELEM = 2048;
constexpr int BATCH  = 4096;
constexpr int BLOCK  = 256;                  // 4 waves/block
constexpr int TASKS  = 3 * BATCH;            // 12288 (pair,row) tasks
constexpr int GRID1  = 512;                  // 2 blocks/CU
constexpr int WAVES  = GRID1 * (BLOCK / 64); // 2048 waves
constexpr int TPW    = TASKS / WAVES;        // 6 contiguous tasks per wave
static_assert(TASKS % WAVES == 0, "tasks must divide evenly");

typedef float f32x4 __attribute__((ext_vector_type(4)));

// One set = half a row: 4 KB of o + 4 KB of t = 8 dwordx4 loads. No waitcnt
// inside; completion claimed later via counted vmcnt. "=&v" early-clobber
// required (load returns race the address inputs otherwise — R3 lesson).
#define DECL8(P) f32x4 P##o0, P##o1, P##o2, P##o3, P##t0, P##t1, P##t2, P##t3;

#define BURST8(P, OB, TB)                                                   \
    asm volatile(                                                           \
        "global_load_dwordx4 %0, %[ob], off\n\t"                            \
        "global_load_dwordx4 %1, %[ob], off offset:1024\n\t"                \
        "global_load_dwordx4 %2, %[ob], off offset:2048\n\t"                \
        "global_load_dwordx4 %3, %[ob], off offset:3072\n\t"                \
        "global_load_dwordx4 %4, %[tb], off\n\t"                            \
        "global_load_dwordx4 %5, %[tb], off offset:1024\n\t"                \
        "global_load_dwordx4 %6, %[tb], off offset:2048\n\t"                \
        "global_load_dwordx4 %7, %[tb], off offset:3072"                    \
        : "=&v"(P##o0), "=&v"(P##o1), "=&v"(P##o2), "=&v"(P##o3),           \
          "=&v"(P##t0), "=&v"(P##t1), "=&v"(P##t2), "=&v"(P##t3)            \
        : [ob] "v"(OB), [tb] "v"(TB)                                        \
        : "memory");

// Counted waits + sched_barrier(0) (rule 18: hipcc hoists register-only ops
// past inline-asm waitcnt despite "memory").
#define WAITV8 asm volatile("s_waitcnt vmcnt(8)" ::: "memory"); \
               __builtin_amdgcn_sched_barrier(0);
#define WAITV0 asm volatile("s_waitcnt vmcnt(0)" ::: "memory"); \
               __builtin_amdgcn_sched_barrier(0);

#define ACC(OV, TV)                                                  \
    {                                                                \
        float d0 = OV[0] - TV[0];                                    \
        float d1 = OV[1] - TV[1];                                    \
        float d2 = OV[2] - TV[2];                                    \
        float d3 = OV[3] - TV[3];                                    \
        ssd0 += d0 * d0 + d1 * d1;                                   \
        ssd1 += d2 * d2 + d3 * d3;                                   \
        mx0 = fmaxf(mx0, fmaxf(TV[0], TV[1]));                       \
        mx1 = fmaxf(mx1, fmaxf(TV[2], TV[3]));                       \
        mn0 = fminf(mn0, fminf(TV[0], TV[1]));                       \
        mn1 = fminf(mn1, fminf(TV[2], TV[3]));                       \
    }

#define COMPUTE8(P) ACC(P##o0, P##t0) ACC(P##o1, P##t1) \
                    ACC(P##o2, P##t2) ACC(P##o3, P##t3)

__global__ __launch_bounds__(BLOCK, 1)   // min 1 wave/EU: truly uncap VGPRs
void wnrmse_stage1(const float* __restrict__ o1, const float* __restrict__ t1,
                   const float* __restrict__ o2, const float* __restrict__ t2,
                   const float* __restrict__ o3, const float* __restrict__ t3,
                   float* __restrict__ partial)
{
    const int tid  = threadIdx.x;
    const int wave = tid >> 6;
    const int lane = tid & 63;

    // XCD-contiguous swizzle: XCD x (default round-robin bid%8) gets the
    // contiguous block range [x*64, (x+1)*64) -> one ~25 MB span per XCD.
    const int bid  = (int)blockIdx.x;
    const int swz  = (bid & 7) * (GRID1 / 8) + (bid >> 3);
    const int gw   = swz * (BLOCK / 64) + wave;          // 0..2047
    const int base = gw * TPW;                           // 6 contiguous tasks

    struct Addr { const float* olo; const float* ohi;
                  const float* tlo; const float* thi; float w; };
    auto decode = [&](int task, Addr& a) {
        const int pair = task >> 12;          // wave-uniform
        const int row  = task & (BATCH - 1);
        const float* ob = (pair == 0) ? o1 : ((pair == 1) ? o2 : o3);
        const float* tb = (pair == 0) ? t1 : ((pair == 1) ? t2 : t3);
        a.olo = ob + (size_t)row * N_ELEM + lane * 4;
        a.ohi = a.olo + 1024;                 // +4096 B: second half-row
        a.tlo = tb + (size_t)row * N_ELEM + lane * 4;
        a.thi = a.tlo + 1024;
        a.w   = (pair == 0) ? 0.50f : 0.25f;
    };

    float local = 0.0f;
    DECL8(A) DECL8(B)          // 2 sets x 32 VGPRs = 64 data VGPRs

    Addr k, kn;
    decode(base, k);
    BURST8(A, k.olo, k.tlo)    // T0 half0: 8 outstanding
    BURST8(B, k.ohi, k.thi)    // T0 half1: 16 outstanding

#pragma unroll
    for (int i = 0; i < TPW; ++i) {          // fully unrolled: no dyn indexing
        if (i + 1 < TPW) decode(base + i + 1, kn);

        float ssd0 = 0.0f, ssd1 = 0.0f;
        float mx0 = -INFINITY, mx1 = -INFINITY;
        float mn0 =  INFINITY, mn1 =  INFINITY;

        WAITV8                               // half0 landed; half1 in flight
        COMPUTE8(A)
        if (i + 1 < TPW) BURST8(A, kn.olo, kn.tlo)   // back to 16 outstanding

        if (i + 1 < TPW) { WAITV8 }          // half1 landed; next half0 flying
        else             { WAITV0 }          // final drain (only at the end)
        COMPUTE8(B)
        if (i + 1 < TPW) BURST8(B, kn.ohi, kn.thi)

        float ssd = ssd0 + ssd1;
        float mx  = fmaxf(mx0, mx1);
        float mn  = fminf(mn0, mn1);
#pragma unroll
        for (int off = 32; off > 0; off >>= 1) {
            ssd += __shfl_xor(ssd, off, 64);
            mx   = fmaxf(mx, __shfl_xor(mx, off, 64));
            mn   = fminf(mn, __shfl_xor(mn, off, 64));
        }
        local += k.w * sqrtf(ssd * (1.0f / (float)N_ELEM)) / (mx - mn);

        k = kn;                              // registers, compile-time copy
    }

    // Per-block combine, one plain store per block.
    __shared__ float s_part[BLOCK / 64];
    if (lane == 0) s_part[wave] = local;
    __syncthreads();
    if (tid == 0) {
        partial[blockIdx.x] = s_part[0] + s_part[1] + s_part[2] + s_part[3];
    }
}

// Stage 2: one block reduces GRID1 partials and writes the final scalar.
__global__ __launch_bounds__(BLOCK)
void wnrmse_stage2(const float* __restrict__ partial, float* __restrict__ out)
{
    const int tid = threadIdx.x;
    float s = 0.0f;
    for (int i = tid; i < GRID1; i += BLOCK) s += partial[i];

#pragma unroll
    for (int off = 32; off > 0; off >>= 1) s += __shfl_xor(s, off, 64);

    __shared__ float s_part[BLOCK / 64];
    const int wave = tid >> 6;
    const int lane = tid & 63;
    if (lane == 0) s_part[wave] = s;
    __syncthreads();
    if (tid == 0) {
        float tot = s_part[0] + s_part[1] + s_part[2] + s_part[3];
        out[0] = tot * (1.0f / (float)BATCH);
    }
}

extern "C" void kernel_launch(void* const* d_in, const int* in_sizes, int n_in,
                              void* d_out, int out_size, void* d_ws, size_t ws_size,
                              hipStream_t stream) {
    const float* o1 = (const float*)d_in[0];
    const float* t1 = (const float*)d_in[1];
    const float* o2 = (const float*)d_in[2];
    const float* t2 = (const float*)d_in[3];
    const float* o3 = (const float*)d_in[4];
    const float* t3 = (const float*)d_in[5];
    float* out     = (float*)d_out;
    float* partial = (float*)d_ws;    // GRID1 floats = 2 KiB, fully overwritten

    wnrmse_stage1<<<GRID1, BLOCK, 0, stream>>>(o1, t1, o2, t2, o3, t3, partial);
    wnrmse_stage2<<<1, BLOCK, 0, stream>>>(partial, out);
}

// Round 10
// 203.142 us; speedup vs baseline: 1.0411x; 1.0411x over previous
//
#include <hip/hip_runtime.h>
#include <math.h>

// loss = mean_b[ 0.5*nrmse(o1,t1) + 0.25*nrmse(o2,t2) + 0.25*nrmse(o3,t3) ]
// B=4096 rows, N=2048 fp32. 201.3 MB in, 4 B out.
//
// FINAL (R10 = R5 revert). Investigation summary:
//   R1: compiler-serialized loads, 74 us (2.72 TB/s read).
//   R5: asm 16-load burst (this kernel), 71 us (2.83 TB/s) — BEST.
//   R7: per-thread zero-drain streaming, 80 us (wave-scattered TA cost).
//   R6/R8/R9: persistent pipelines — allocator spills asm burst sets
//     (VGPR pinned 68-80 even with launch_bounds(256,1); 14-21 MB scratch).
// Read rate is invariant at ~2.8 TB/s across 6x in-flight-byte range and
// three structures -> read-direction service path saturated (m13 copy =
// 3.15 TB/s/direction is the machine's best; we are at 89%). VALU 7%,
// LDS 0, occupancy non-binding. Stage1 is at its pattern roofline;
// remaining ~130 us of dur_us is fixed harness overhead (invariant R1-R9).
constexpr int N_ELEM = 2048;
constexpr int BATCH  = 4096;
constexpr int BLOCK  = 256;                   // 4 waves/block
constexpr int TASKS  = 3 * BATCH;             // 12288 (pair,row) tasks
constexpr int GRID1  = TASKS / (BLOCK / 64);  // 3072 blocks, 1 task/wave

typedef float f32x4 __attribute__((ext_vector_type(4)));

__global__ __launch_bounds__(BLOCK)
void wnrmse_stage1(const float* __restrict__ o1, const float* __restrict__ t1,
                   const float* __restrict__ o2, const float* __restrict__ t2,
                   const float* __restrict__ o3, const float* __restrict__ t3,
                   float* __restrict__ partial)
{
    const int tid  = threadIdx.x;
    const int wave = tid >> 6;
    const int lane = tid & 63;
    const int task = blockIdx.x * (BLOCK / 64) + wave;   // global wave id == task

    const int pair = task >> 12;          // wave-uniform
    const int row  = task & (BATCH - 1);

    const float* ob = (pair == 0) ? o1 : ((pair == 1) ? o2 : o3);
    const float* tb = (pair == 0) ? t1 : ((pair == 1) ? t2 : t3);
    const float  wgt = (pair == 0) ? 0.50f : 0.25f;

    // Chunk j (j=0..7) for this lane: byte offset lane*16 + j*1024 from row
    // base. 13-bit signed imm covers j=0..3 per base -> lo and hi(+4096B).
    const float* o_lo = ob + (size_t)row * N_ELEM + lane * 4;
    const float* o_hi = o_lo + 1024;   // +4096 bytes
    const float* t_lo = tb + (size_t)row * N_ELEM + lane * 4;
    const float* t_hi = t_lo + 1024;

    f32x4 ov0, ov1, ov2, ov3, ov4, ov5, ov6, ov7;
    f32x4 tv0, tv1, tv2, tv3, tv4, tv5, tv6, tv7;

    // All 16 loads issued back-to-back; ONE waitcnt at the end of the block.
    // 16 KB outstanding per wave. "=&v" (early-clobber) is REQUIRED: load
    // returns arrive while later loads still read the address inputs.
    asm volatile(
        "global_load_dwordx4 %0,  %[olo], off\n\t"
        "global_load_dwordx4 %1,  %[olo], off offset:1024\n\t"
        "global_load_dwordx4 %2,  %[olo], off offset:2048\n\t"
        "global_load_dwordx4 %3,  %[olo], off offset:3072\n\t"
        "global_load_dwordx4 %4,  %[ohi], off\n\t"
        "global_load_dwordx4 %5,  %[ohi], off offset:1024\n\t"
        "global_load_dwordx4 %6,  %[ohi], off offset:2048\n\t"
        "global_load_dwordx4 %7,  %[ohi], off offset:3072\n\t"
        "global_load_dwordx4 %8,  %[tlo], off\n\t"
        "global_load_dwordx4 %9,  %[tlo], off offset:1024\n\t"
        "global_load_dwordx4 %10, %[tlo], off offset:2048\n\t"
        "global_load_dwordx4 %11, %[tlo], off offset:3072\n\t"
        "global_load_dwordx4 %12, %[thi], off\n\t"
        "global_load_dwordx4 %13, %[thi], off offset:1024\n\t"
        "global_load_dwordx4 %14, %[thi], off offset:2048\n\t"
        "global_load_dwordx4 %15, %[thi], off offset:3072\n\t"
        "s_waitcnt vmcnt(0)"
        : "=&v"(ov0), "=&v"(ov1), "=&v"(ov2), "=&v"(ov3),
          "=&v"(ov4), "=&v"(ov5), "=&v"(ov6), "=&v"(ov7),
          "=&v"(tv0), "=&v"(tv1), "=&v"(tv2), "=&v"(tv3),
          "=&v"(tv4), "=&v"(tv5), "=&v"(tv6), "=&v"(tv7)
        : [olo] "v"(o_lo), [ohi] "v"(o_hi),
          [tlo] "v"(t_lo), [thi] "v"(t_hi)
        : "memory");

    // Compute phase. Split accumulators to shorten dep chains.
    float ssd0 = 0.0f, ssd1 = 0.0f;
    float tmax0 = -INFINITY, tmax1 = -INFINITY;
    float tmin0 =  INFINITY, tmin1 =  INFINITY;

#define ACC(OV, TV)                                                       \
    {                                                                     \
        float d0 = OV[0] - TV[0];                                         \
        float d1 = OV[1] - TV[1];                                         \
        float d2 = OV[2] - TV[2];                                         \
        float d3 = OV[3] - TV[3];                                         \
        ssd0 += d0 * d0 + d1 * d1;                                        \
        ssd1 += d2 * d2 + d3 * d3;                                        \
        tmax0 = fmaxf(tmax0, fmaxf(TV[0], TV[1]));                        \
        tmax1 = fmaxf(tmax1, fmaxf(TV[2], TV[3]));                        \
        tmin0 = fminf(tmin0, fminf(TV[0], TV[1]));                        \
        tmin1 = fminf(tmin1, fminf(TV[2], TV[3]));                        \
    }
    ACC(ov0, tv0) ACC(ov1, tv1) ACC(ov2, tv2) ACC(ov3, tv3)
    ACC(ov4, tv4) ACC(ov5, tv5) ACC(ov6, tv6) ACC(ov7, tv7)
#undef ACC

    float ssd  = ssd0 + ssd1;
    float tmax = fmaxf(tmax0, tmax1);
    float tmin = fminf(tmin0, tmin1);

    // Wave-64 butterfly reduce; all lanes end with the row result.
#pragma unroll
    for (int off = 32; off > 0; off >>= 1) {
        ssd  += __shfl_xor(ssd, off, 64);
        tmax  = fmaxf(tmax, __shfl_xor(tmax, off, 64));
        tmin  = fminf(tmin, __shfl_xor(tmin, off, 64));
    }

    const float rmse  = sqrtf(ssd * (1.0f / (float)N_ELEM));
    const float local = wgt * rmse / (tmax - tmin);

    // Per-block combine, one plain store per block.
    __shared__ float s_part[BLOCK / 64];
    if (lane == 0) s_part[wave] = local;
    __syncthreads();
    if (tid == 0) {
        partial[blockIdx.x] = s_part[0] + s_part[1] + s_part[2] + s_part[3];
    }
}

// Stage 2: one block reduces GRID1 partials and writes the final scalar.
__global__ __launch_bounds__(BLOCK)
void wnrmse_stage2(const float* __restrict__ partial, float* __restrict__ out)
{
    const int tid = threadIdx.x;
    float s = 0.0f;
    for (int i = tid; i < GRID1; i += BLOCK) s += partial[i];

#pragma unroll
    for (int off = 32; off > 0; off >>= 1) s += __shfl_xor(s, off, 64);

    __shared__ float s_part[BLOCK / 64];
    const int wave = tid >> 6;
    const int lane = tid & 63;
    if (lane == 0) s_part[wave] = s;
    __syncthreads();
    if (tid == 0) {
        float tot = s_part[0] + s_part[1] + s_part[2] + s_part[3];
        out[0] = tot * (1.0f / (float)BATCH);
    }
}

extern "C" void kernel_launch(void* const* d_in, const int* in_sizes, int n_in,
                              void* d_out, int out_size, void* d_ws, size_t ws_size,
                              hipStream_t stream) {
    const float* o1 = (const float*)d_in[0];
    const float* t1 = (const float*)d_in[1];
    const float* o2 = (const float*)d_in[2];
    const float* t2 = (const float*)d_in[3];
    const float* o3 = (const float*)d_in[4];
    const float* t3 = (const float*)d_in[5];
    float* out     = (float*)d_out;
    float* partial = (float*)d_ws;    // GRID1 floats = 12 KiB, fully overwritten

    wnrmse_stage1<<<GRID1, BLOCK, 0, stream>>>(o1, t1, o2, t2, o3, t3, partial);
    wnrmse_stage2<<<1, BLOCK, 0, stream>>>(partial, out);
}